// Round 9
// baseline (71.883 us; speedup 1.0000x reference)
//
#include <hip/hip_runtime.h>

#define NN 8192
#define DIM 128

typedef short short8 __attribute__((ext_vector_type(8)));
typedef float f32x4 __attribute__((ext_vector_type(4)));

__device__ __forceinline__ unsigned short f2bf(float f) {
  unsigned int u = __float_as_uint(f);
  u = (u + 0x7FFFu + ((u >> 16) & 1u)) >> 16;
  return (unsigned short)u;
}
__device__ __forceinline__ unsigned int cvtpk(float a, float b) {
  unsigned int r;
  asm("v_cvt_pk_bf16_f32 %0, %1, %2" : "=v"(r) : "v"(a), "v"(b));
  return r;
}
__device__ __forceinline__ void gll16(const void* gsrc, void* ldst) {
  __builtin_amdgcn_global_load_lds(
      (const __attribute__((address_space(1))) unsigned int*)gsrc,
      (__attribute__((address_space(3))) unsigned int*)ldst, 16, 0, 0);
}
#define BAR_LGKM()                                          \
  do {                                                      \
    asm volatile("s_waitcnt lgkmcnt(0)" ::: "memory");      \
    __builtin_amdgcn_sched_barrier(0);                      \
    __builtin_amdgcn_s_barrier();                           \
    __builtin_amdgcn_sched_barrier(0);                      \
  } while (0)
#define BAR_VM()                                            \
  do {                                                      \
    asm volatile("s_waitcnt vmcnt(0)" ::: "memory");        \
    __builtin_amdgcn_sched_barrier(0);                      \
    __builtin_amdgcn_s_barrier();                           \
    __builtin_amdgcn_sched_barrier(0);                      \
  } while (0)

// ---------------------------------------------------------------------------
// PREP: blocks 0..1023:  x -> bf16 swizzled tile images (8 MB)
//       blocks 1024..1031: per-head centered W_kv^T bf16 swizzled image
//       blocks 1032..1039: zero `dots`
// x tile image (16 KB per (b,tile64)): byte = r*256 + ((2c) ^ ((r&7)<<4))
// W image (32 KB per head):            byte = c*256 + ((2k) ^ ((c&7)<<4))
// ---------------------------------------------------------------------------
__global__ __launch_bounds__(256) void prep_kernel(const float* __restrict__ x,
                                                   const float* __restrict__ wqkv,
                                                   unsigned char* __restrict__ ximg,
                                                   unsigned char* __restrict__ wimg,
                                                   float* __restrict__ dots) {
  __shared__ __align__(16) unsigned char wb[32768];
  const int t = threadIdx.x;
  const int bx = blockIdx.x;
  if (bx < 1024) {
#pragma unroll
    for (int rep = 0; rep < 2; ++rep) {
      const int idx = bx * 512 + rep * 256 + t;  // 16B chunk index, 0..524287
      const int bt = idx >> 10;                  // b*128 + tile
      const int o = (idx & 1023) << 4;           // byte in 16KB image
      const int r = o >> 8;
      const int q0 = o & 255;
      const int c0 = (q0 ^ ((r & 7) << 4)) >> 1;
      const float* src = x + ((size_t)(bt >> 7) * NN + (size_t)(bt & 127) * 64 + r) * DIM + c0;
      const float4 v0 = *(const float4*)src;
      const float4 v1 = *(const float4*)(src + 4);
      uint4 u;
      u.x = cvtpk(v0.x, v0.y);
      u.y = cvtpk(v0.z, v0.w);
      u.z = cvtpk(v1.x, v1.y);
      u.w = cvtpk(v1.z, v1.w);
      *(uint4*)(ximg + (size_t)idx * 16) = u;
    }
  } else if (bx < 1032) {
    const int h = bx - 1024;
    const int k = t >> 1;
    const int chalf = t & 1;
    const float* wp = wqkv + (size_t)k * 1536 + (chalf ? (1024 + h * 64) : (512 + h * 64));
    const float4* wp4 = (const float4*)wp;
    const int c0 = chalf * 64;
    float4 wv[16];
    float sum = 0.f;
#pragma unroll
    for (int jj = 0; jj < 16; ++jj) {
      wv[jj] = wp4[jj];
      sum += wv[jj].x + wv[jj].y + wv[jj].z + wv[jj].w;
    }
    const float mean = sum * (1.f / 64.f);
#pragma unroll
    for (int jj = 0; jj < 16; ++jj) {
      const int c = c0 + jj * 4;
      const unsigned int cx0 = (unsigned int)((c + 0) & 7) << 4;
      const unsigned int cx1 = (unsigned int)((c + 1) & 7) << 4;
      const unsigned int cx2 = (unsigned int)((c + 2) & 7) << 4;
      const unsigned int cx3 = (unsigned int)((c + 3) & 7) << 4;
      *(unsigned short*)(wb + (c + 0) * 256 + (((unsigned)(2 * k)) ^ cx0)) = f2bf(wv[jj].x - mean);
      *(unsigned short*)(wb + (c + 1) * 256 + (((unsigned)(2 * k)) ^ cx1)) = f2bf(wv[jj].y - mean);
      *(unsigned short*)(wb + (c + 2) * 256 + (((unsigned)(2 * k)) ^ cx2)) = f2bf(wv[jj].z - mean);
      *(unsigned short*)(wb + (c + 3) * 256 + (((unsigned)(2 * k)) ^ cx3)) = f2bf(wv[jj].w - mean);
    }
    __syncthreads();
    const uint4* s4 = (const uint4*)(wb + t * 128);
    uint4* d4 = (uint4*)(wimg + (size_t)h * 32768 + t * 128);
#pragma unroll
    for (int i = 0; i < 8; ++i) d4[i] = s4[i];
  } else {
    const int zb = bx - 1032;
    float4* dz = (float4*)dots + (size_t)zb * 4096 + t;
    const float4 z = make_float4(0.f, 0.f, 0.f, 0.f);
#pragma unroll
    for (int i = 0; i < 16; ++i) dz[i * 256] = z;
  }
}

// ---------------------------------------------------------------------------
// K1 v3: wave-private pipeline. 512 threads, 8 waves; block = (b,h,chunk256).
// Wave w owns rows [32w, 32w+32): private gll16 x-stage -> 64 kv MFMA ->
// in-register variance -> KT/VT written over its own x region (no barrier,
// same-wave DS order + acc data dependence). ONE mid barrier, then dots
// phase: wave (dt=w>>1, ehalf=w&1) reads all 8 subtiles' KT/VT.
// LDS: WB 32KB + 8 x 8KB = 96KB. Barriers per block: 2.
// KT/VT layout: base + d*64 + (((row>>2)*8) ^ ((d&3)<<4)) + (row&3)*2.
// ---------------------------------------------------------------------------
__global__ __launch_bounds__(512) void kv_dots_v3(const unsigned char* __restrict__ ximg,
                                                  const unsigned char* __restrict__ wimg,
                                                  float* __restrict__ dots) {
  __shared__ __align__(16) unsigned char smem[98304];
  unsigned char* const WB = smem;  // 32 KB

  const int t = threadIdx.x;
  const int bx = blockIdx.x;
  const int h = bx >> 7;
  const int p = bx & 127;
  const int b = p >> 5;
  const int chunk = p & 31;

  const int wave = t >> 6;
  const int lane = t & 63;
  const int lb = lane & 15;
  const int kg = lane >> 4;
  const unsigned int lxor = (unsigned int)(lb & 7) << 4;
  const unsigned int rxor2 = (unsigned int)(lb & 3) << 4;

  unsigned char* const PW = smem + 32768 + wave * 8192;  // private: x then kT|vT

  // ---- stage W (cooperative) + own x subtile (wave-private) ----
  {
    const unsigned char* wsrc = wimg + (size_t)h * 32768;
#pragma unroll
    for (int i = 0; i < 4; ++i)
      gll16(wsrc + (wave * 4 + i) * 1024 + lane * 16, WB + (wave * 4 + i) * 1024);
    const unsigned char* xsrc = ximg +
        (size_t)(b * 128 + chunk * 4 + (wave >> 1)) * 16384 + (size_t)(wave & 1) * 8192;
#pragma unroll
    for (int i = 0; i < 8; ++i)
      gll16(xsrc + i * 1024 + lane * 16, PW + i * 1024);
  }
  BAR_VM();

  // ---- kv = x @ W' via MFMA: acc[rg][ct], rows rg*16 + kg*4 + reg ----
  f32x4 acc[2][8];
#pragma unroll
  for (int rg = 0; rg < 2; ++rg)
#pragma unroll
    for (int ct = 0; ct < 8; ++ct) acc[rg][ct] = (f32x4)0.f;

#pragma unroll
  for (int ks = 0; ks < 4; ++ks) {
    const unsigned int koff = (unsigned int)(ks * 64 + kg * 16);
#pragma unroll
    for (int rg = 0; rg < 2; ++rg) {
      const short8 a = *(const short8*)(PW + (rg * 16 + lb) * 256 + (koff ^ lxor));
#pragma unroll
      for (int ct = 0; ct < 8; ++ct) {
        const short8 bf = *(const short8*)(WB + (ct * 16 + lb) * 256 + (koff ^ lxor));
        acc[rg][ct] = __builtin_amdgcn_mfma_f32_16x16x32_bf16(a, bf, acc[rg][ct], 0, 0, 0);
      }
    }
  }

  // ---- per-row variance (inputs centered via W'): kscale = s_k*s_v ----
  float ks[2][4];
#pragma unroll
  for (int rg = 0; rg < 2; ++rg) {
#pragma unroll
    for (int e = 0; e < 4; ++e) {
      float sk = acc[rg][0][e] * acc[rg][0][e] + acc[rg][1][e] * acc[rg][1][e] +
                 acc[rg][2][e] * acc[rg][2][e] + acc[rg][3][e] * acc[rg][3][e];
      float sv = acc[rg][4][e] * acc[rg][4][e] + acc[rg][5][e] * acc[rg][5][e] +
                 acc[rg][6][e] * acc[rg][6][e] + acc[rg][7][e] * acc[rg][7][e];
      sk += __shfl_xor(sk, 1); sv += __shfl_xor(sv, 1);
      sk += __shfl_xor(sk, 2); sv += __shfl_xor(sv, 2);
      sk += __shfl_xor(sk, 4); sv += __shfl_xor(sv, 4);
      sk += __shfl_xor(sk, 8); sv += __shfl_xor(sv, 8);
      ks[rg][e] = rsqrtf(sk * (1.f / 64.f) + 1e-5f) * rsqrtf(sv * (1.f / 64.f) + 1e-5f);
    }
  }
  __builtin_amdgcn_sched_barrier(0);  // keep x reads strictly before overlay writes

  // ---- overlay write: kT [0,4K) scaled, vT [4K,8K) raw ----
#pragma unroll
  for (int rg = 0; rg < 2; ++rg) {
    const unsigned int rb = ((unsigned int)(rg * 32 + kg * 8)) ^ rxor2;
#pragma unroll
    for (int ct = 0; ct < 4; ++ct) {
      uint2 w;
      w.x = cvtpk(acc[rg][ct][0] * ks[rg][0], acc[rg][ct][1] * ks[rg][1]);
      w.y = cvtpk(acc[rg][ct][2] * ks[rg][2], acc[rg][ct][3] * ks[rg][3]);
      *(uint2*)(PW + (ct * 16 + lb) * 64 + rb) = w;
    }
#pragma unroll
    for (int ct = 4; ct < 8; ++ct) {
      uint2 w;
      w.x = cvtpk(acc[rg][ct][0], acc[rg][ct][1]);
      w.y = cvtpk(acc[rg][ct][2], acc[rg][ct][3]);
      *(uint2*)(PW + 4096 + (ct - 4) * 1024 + lb * 64 + rb) = w;
    }
  }
  BAR_LGKM();

  // ---- dots phase: wave (dt, ehalf) over all 8 subtiles ----
  const int dt = wave >> 1;
  const int ntb = (wave & 1) * 2;
  f32x4 dacc[2];
  dacc[0] = (f32x4)0.f;
  dacc[1] = (f32x4)0.f;
  const unsigned int soff = ((unsigned int)(kg * 16)) ^ rxor2;
#pragma unroll
  for (int s = 0; s < 8; ++s) {
    const unsigned char* P = smem + 32768 + s * 8192;
    const short8 a = *(const short8*)(P + (dt * 16 + lb) * 64 + soff);
#pragma unroll
    for (int j = 0; j < 2; ++j) {
      const short8 bf = *(const short8*)(P + 4096 + ((ntb + j) * 16 + lb) * 64 + soff);
      dacc[j] = __builtin_amdgcn_mfma_f32_16x16x32_bf16(a, bf, dacc[j], 0, 0, 0);
    }
  }

  float* dp = dots + (size_t)(b * 8 + h) * 4096;
#pragma unroll
  for (int j = 0; j < 2; ++j) {
#pragma unroll
    for (int reg = 0; reg < 4; ++reg) {
      const int d = dt * 16 + kg * 4 + reg;
      const int e = (ntb + j) * 16 + lb;
      atomicAdd(&dp[d * 64 + e], dacc[j][reg]);
    }
  }
}

// ---------------------------------------------------------------------------
// K2 (fused t + bigw), c-split. TR=1: store part transposed [j][c].
// ---------------------------------------------------------------------------
template <int TR>
__global__ __launch_bounds__(256) void tw_kernel(const float* __restrict__ wqkv,
                                                 const float* __restrict__ wout,
                                                 const float* __restrict__ dots,
                                                 float* __restrict__ part) {
  __shared__ __align__(16) float ds[64 * 66];
  __shared__ __align__(16) float wqT[64 * 36];
  __shared__ __align__(16) float Ts[32 * 66];
  __shared__ __align__(16) float wos[64 * 132];

  const int blk = blockIdx.x;
  const int bh = blk >> 2;
  const int cq = blk & 3;
  const int h = bh & 7;
  const int t = threadIdx.x;

  for (int i = t; i < 4096; i += 256)
    ds[(i >> 6) * 66 + (i & 63)] = dots[(size_t)bh * 4096 + i];

  for (int i = t; i < 2048; i += 256) {
    const int d = i >> 5;
    const int c = i & 31;
    wqT[d * 36 + c] = wqkv[(size_t)(cq * 32 + c) * 1536 + h * 64 + d];
  }

  for (int i = t; i < 2048; i += 256) {
    const int e = i >> 5;
    const int jj = (i & 31) * 4;
    *(float4*)&wos[e * 132 + jj] = *(const float4*)(wout + (size_t)(h * 64 + e) * 128 + jj);
  }
  __syncthreads();

  {
    const int c = t >> 3;
    const int e0 = (t & 7) * 8;
    float acc[8];
#pragma unroll
    for (int q = 0; q < 8; ++q) acc[q] = 0.f;
    for (int d = 0; d < 64; ++d) {
      const float wq = wqT[d * 36 + c];
      const float4 d0 = *(const float4*)&ds[d * 66 + e0];
      const float4 d1 = *(const float4*)&ds[d * 66 + e0 + 4];
      acc[0] += wq * d0.x; acc[1] += wq * d0.y; acc[2] += wq * d0.z; acc[3] += wq * d0.w;
      acc[4] += wq * d1.x; acc[5] += wq * d1.y; acc[6] += wq * d1.z; acc[7] += wq * d1.w;
    }
    *(float4*)&Ts[c * 66 + e0] = make_float4(acc[0], acc[1], acc[2], acc[3]);
    *(float4*)&Ts[c * 66 + e0 + 4] = make_float4(acc[4], acc[5], acc[6], acc[7]);
  }
  __syncthreads();

  {
    const int c = t >> 3;
    const int j0 = (t & 7) * 16;
    float acc[16];
#pragma unroll
    for (int q = 0; q < 16; ++q) acc[q] = 0.f;
    for (int e = 0; e < 64; ++e) {
      const float tv = Ts[c * 66 + e];
#pragma unroll
      for (int q = 0; q < 16; q += 4) {
        const float4 wv = *(const float4*)&wos[e * 132 + j0 + q];
        acc[q + 0] += tv * wv.x;
        acc[q + 1] += tv * wv.y;
        acc[q + 2] += tv * wv.z;
        acc[q + 3] += tv * wv.w;
      }
    }
    if (TR) {
      float* pp = part + (size_t)bh * 16384;
      const int cc = cq * 32 + c;
#pragma unroll
      for (int q = 0; q < 16; ++q) pp[(j0 + q) * 128 + cc] = acc[q];
    } else {
      float* pp = part + (size_t)bh * 16384 + (size_t)(cq * 32 + c) * 128 + j0;
#pragma unroll
      for (int q = 0; q < 16; q += 4)
        *(float4*)&pp[q] = make_float4(acc[q], acc[q + 1], acc[q + 2], acc[q + 3]);
    }
  }
}

// ---------------------------------------------------------------------------
// K2r v2: bigwimg (bf16, swizzled) = (1/n) * sum_h part_T[b,h][j][c]
// ---------------------------------------------------------------------------
__global__ __launch_bounds__(256) void bigw_reduce_v2(const float* __restrict__ part,
                                                      unsigned char* __restrict__ bigwimg) {
  const int idx = blockIdx.x * 256 + threadIdx.x;  // 16B chunk, 0..8191
  const int b = idx >> 11;
  const int o = (idx & 2047) << 4;
  const int j = o >> 8;
  const int q0 = o & 255;
  const int c0 = (q0 ^ ((j & 7) << 4)) >> 1;
  float s[8];
#pragma unroll
  for (int i = 0; i < 8; ++i) s[i] = 0.f;
  const float* pb = part + (size_t)b * 8 * 16384 + j * 128 + c0;
#pragma unroll
  for (int hh = 0; hh < 8; ++hh) {
    const float4 p0 = *(const float4*)(pb + hh * 16384);
    const float4 p1 = *(const float4*)(pb + hh * 16384 + 4);
    s[0] += p0.x; s[1] += p0.y; s[2] += p0.z; s[3] += p0.w;
    s[4] += p1.x; s[5] += p1.y; s[6] += p1.z; s[7] += p1.w;
  }
  const float inv_n = 1.f / (float)NN;
  uint4 u;
  u.x = cvtpk(s[0] * inv_n, s[1] * inv_n);
  u.y = cvtpk(s[2] * inv_n, s[3] * inv_n);
  u.z = cvtpk(s[4] * inv_n, s[5] * inv_n);
  u.w = cvtpk(s[6] * inv_n, s[7] * inv_n);
  *(uint4*)(bigwimg + (size_t)idx * 16) = u;
}

// ---------------------------------------------------------------------------
// K3 v2: out = x @ BigW + bias, pure gll staging. 48 KB LDS, grid 512.
// ---------------------------------------------------------------------------
__global__ __launch_bounds__(256) void out_v2(const unsigned char* __restrict__ ximg,
                                              const unsigned char* __restrict__ bigwimg,
                                              const float* __restrict__ bout,
                                              float* __restrict__ out) {
  __shared__ __align__(16) unsigned char smem[49152];
  unsigned char* const XB = smem;
  unsigned char* const WJ = smem + 16384;

  const int t = threadIdx.x;
  const int bx = blockIdx.x;
  const int b = bx >> 7;
  const int tile = bx & 127;

  const int wave = t >> 6;
  const int lane = t & 63;
  const int lb = lane & 15;
  const int kg = lane >> 4;
  const unsigned int lxor = (unsigned int)(lb & 7) << 4;

  const unsigned char* wsrc = bigwimg + (size_t)b * 32768;
  const unsigned char* xsrc = ximg + (size_t)(b * 128 + tile) * 16384;

#pragma unroll
  for (int i = 0; i < 8; ++i)
    gll16(wsrc + (wave * 8 + i) * 1024 + lane * 16, WJ + (wave * 8 + i) * 1024);
#pragma unroll
  for (int i = 0; i < 4; ++i)
    gll16(xsrc + (wave * 4 + i) * 1024 + lane * 16, XB + (wave * 4 + i) * 1024);

  float bias[8];
#pragma unroll
  for (int ct = 0; ct < 8; ++ct) bias[ct] = bout[ct * 16 + lb];

  BAR_VM();

  f32x4 acc[8];
#pragma unroll
  for (int ct = 0; ct < 8; ++ct) acc[ct] = (f32x4)0.f;
  const int arow = wave * 16 + lb;
#pragma unroll
  for (int ks = 0; ks < 4; ++ks) {
    const unsigned int koff = (unsigned int)(ks * 64 + kg * 16);
    const short8 a = *(const short8*)(XB + arow * 256 + (koff ^ lxor));
#pragma unroll
    for (int ct = 0; ct < 8; ++ct) {
      const short8 bf = *(const short8*)(WJ + (ct * 16 + lb) * 256 + (koff ^ lxor));
      acc[ct] = __builtin_amdgcn_mfma_f32_16x16x32_bf16(a, bf, acc[ct], 0, 0, 0);
    }
  }

  float* op = out + (size_t)(b * NN + tile * 64 + 16 * wave + kg * 4) * DIM;
#pragma unroll
  for (int ct = 0; ct < 8; ++ct) {
#pragma unroll
    for (int reg = 0; reg < 4; ++reg) {
      op[reg * DIM + ct * 16 + lb] = acc[ct][reg] + bias[ct];
    }
  }
}

// ===========================================================================
// Fallback path (R6, known-good) used if ws_size is too small for the images.
// ===========================================================================
__global__ __launch_bounds__(256) void zero_dots_fb(float* __restrict__ dots) {
  float4* dz = (float4*)dots + (size_t)blockIdx.x * 4096 + threadIdx.x;
  const float4 z = make_float4(0.f, 0.f, 0.f, 0.f);
#pragma unroll
  for (int i = 0; i < 16; ++i) dz[i * 256] = z;
}

__global__ __launch_bounds__(256) void kv_dots_fb(const float* __restrict__ x,
                                                  const float* __restrict__ wqkv,
                                                  float* __restrict__ dots) {
  __shared__ __align__(16) unsigned char smem[49152];
  unsigned char* const XB = smem;
  unsigned char* const KT = smem;
  unsigned char* const VT = smem + 8192;
  unsigned char* const WB = smem + 16384;

  const int t = threadIdx.x;
  const int bx = blockIdx.x;
  const int h = bx >> 7;
  const int p = bx & 127;
  const int b = p >> 5;
  const int chunk = p & 31;
  const int row0 = chunk * 256;

  const int wave = t >> 6;
  const int lane = t & 63;
  const int lb = lane & 15;
  const int kg = lane >> 4;
  const unsigned int lxor = (unsigned int)(lb & 7) << 4;

  {
    const int k = t >> 1;
    const int chalf = t & 1;
    const float* wp = wqkv + (size_t)k * 1536 + (chalf ? (1024 + h * 64) : (512 + h * 64));
    const float4* wp4 = (const float4*)wp;
    const int c0 = chalf * 64;
    float4 wv[16];
    float sum = 0.f;
#pragma unroll
    for (int jj = 0; jj < 16; ++jj) {
      wv[jj] = wp4[jj];
      sum += wv[jj].x + wv[jj].y + wv[jj].z + wv[jj].w;
    }
    const float mean = sum * (1.f / 64.f);
#pragma unroll
    for (int jj = 0; jj < 16; ++jj) {
      const int c = c0 + jj * 4;
      const unsigned int cx0 = (unsigned int)((c + 0) & 7) << 4;
      const unsigned int cx1 = (unsigned int)((c + 1) & 7) << 4;
      const unsigned int cx2 = (unsigned int)((c + 2) & 7) << 4;
      const unsigned int cx3 = (unsigned int)((c + 3) & 7) << 4;
      *(unsigned short*)(WB + (c + 0) * 256 + (((unsigned)(2 * k)) ^ cx0)) = f2bf(wv[jj].x - mean);
      *(unsigned short*)(WB + (c + 1) * 256 + (((unsigned)(2 * k)) ^ cx1)) = f2bf(wv[jj].y - mean);
      *(unsigned short*)(WB + (c + 2) * 256 + (((unsigned)(2 * k)) ^ cx2)) = f2bf(wv[jj].z - mean);
      *(unsigned short*)(WB + (c + 3) * 256 + (((unsigned)(2 * k)) ^ cx3)) = f2bf(wv[jj].w - mean);
    }
  }

  f32x4 dacc[4];
#pragma unroll
  for (int nt = 0; nt < 4; ++nt) dacc[nt] = (f32x4)0.f;

  __syncthreads();

  for (int tile = 0; tile < 4; ++tile) {
    const int rowbase = row0 + tile * 64;
    __syncthreads();
    {
      const int r = t >> 2;
      const int cb = (t & 3) * 32;
      const float4* gp4 = (const float4*)(x + (size_t)(b * NN + rowbase + r) * DIM + cb);
      const unsigned int rxor = (unsigned int)(r & 7) << 4;
#pragma unroll
      for (int jj = 0; jj < 4; ++jj) {
        const float4 v0 = gp4[2 * jj];
        const float4 v1 = gp4[2 * jj + 1];
        uint4 u;
        u.x = cvtpk(v0.x, v0.y);
        u.y = cvtpk(v0.z, v0.w);
        u.z = cvtpk(v1.x, v1.y);
        u.w = cvtpk(v1.z, v1.w);
        *(uint4*)(XB + r * 256 + (((unsigned)(2 * cb + 16 * jj)) ^ rxor)) = u;
      }
    }
    __syncthreads();

    f32x4 acc[8];
#pragma unroll
    for (int ct = 0; ct < 8; ++ct) acc[ct] = (f32x4)0.f;
    const int arow = wave * 16 + lb;
#pragma unroll
    for (int ks = 0; ks < 4; ++ks) {
      const unsigned int koff = (unsigned int)(ks * 64 + kg * 16);
      const short8 a = *(const short8*)(XB + arow * 256 + (koff ^ lxor));
#pragma unroll
      for (int ct = 0; ct < 8; ++ct) {
        const short8 bf = *(const short8*)(WB + (ct * 16 + lb) * 256 + (koff ^ lxor));
        acc[ct] = __builtin_amdgcn_mfma_f32_16x16x32_bf16(a, bf, acc[ct], 0, 0, 0);
      }
    }

    float kscale[4];
#pragma unroll
    for (int e = 0; e < 4; ++e) {
      float sk = acc[0][e] * acc[0][e] + acc[1][e] * acc[1][e] +
                 acc[2][e] * acc[2][e] + acc[3][e] * acc[3][e];
      float sv = acc[4][e] * acc[4][e] + acc[5][e] * acc[5][e] +
                 acc[6][e] * acc[6][e] + acc[7][e] * acc[7][e];
      sk += __shfl_xor(sk, 1); sv += __shfl_xor(sv, 1);
      sk += __shfl_xor(sk, 2); sv += __shfl_xor(sv, 2);
      sk += __shfl_xor(sk, 4); sv += __shfl_xor(sv, 4);
      sk += __shfl_xor(sk, 8); sv += __shfl_xor(sv, 8);
      kscale[e] = rsqrtf(sk * (1.f / 64.f) + 1e-5f) * rsqrtf(sv * (1.f / 64.f) + 1e-5f);
    }

    __syncthreads();
    {
      const unsigned int rb2 = (unsigned int)(32 * wave + kg * 8);
#pragma unroll
      for (int ct = 0; ct < 4; ++ct) {
        uint2 w;
        w.x = cvtpk(acc[ct][0] * kscale[0], acc[ct][1] * kscale[1]);
        w.y = cvtpk(acc[ct][2] * kscale[2], acc[ct][3] * kscale[3]);
        *(uint2*)(KT + (ct * 16 + lb) * 128 + (rb2 ^ lxor)) = w;
      }
#pragma unroll
      for (int ct = 4; ct < 8; ++ct) {
        uint2 w;
        w.x = cvtpk(acc[ct][0], acc[ct][1]);
        w.y = cvtpk(acc[ct][2], acc[ct][3]);
        *(uint2*)(VT + ((ct - 4) * 16 + lb) * 128 + (rb2 ^ lxor)) = w;
      }
    }
    __syncthreads();

#pragma unroll
    for (int ks2 = 0; ks2 < 2; ++ks2) {
      const unsigned int koff = (unsigned int)(ks2 * 64 + kg * 16);
      const short8 a = *(const short8*)(KT + (wave * 16 + lb) * 128 + (koff ^ lxor));
#pragma unroll
      for (int nt = 0; nt < 4; ++nt) {
        const short8 bf = *(const short8*)(VT + (nt * 16 + lb) * 128 + (koff ^ lxor));
        dacc[nt] = __builtin_amdgcn_mfma_f32_16x16x32_bf16(a, bf, dacc[nt], 0, 0, 0);
      }
    }
  }

  float* dp = dots + (size_t)(b * 8 + h) * 4096;
#pragma unroll
  for (int nt = 0; nt < 4; ++nt) {
#pragma unroll
    for (int reg = 0; reg < 4; ++reg) {
      const int d = 16 * wave + kg * 4 + reg;
      const int e = nt * 16 + lb;
      atomicAdd(&dp[d * 64 + e], dacc[nt][reg]);
    }
  }
}

__global__ __launch_bounds__(256) void bigw_reduce_fb(const float* __restrict__ part,
                                                      float* __restrict__ bigw) {
  const int i = blockIdx.x * 256 + threadIdx.x;
  const int b = i >> 14;
  const int cj = i & 16383;
  const float* pp = part + (size_t)b * 8 * 16384 + cj;
  float s = 0.f;
#pragma unroll
  for (int h = 0; h < 8; ++h) s += pp[h * 16384];
  bigw[i] = s * (1.f / (float)NN);
}

__global__ __launch_bounds__(256) void out_fb(const float* __restrict__ x,
                                              const float* __restrict__ bigw,
                                              const float* __restrict__ bout,
                                              float* __restrict__ out) {
  __shared__ __align__(16) unsigned char smem[49152];
  unsigned char* const XB = smem;
  unsigned char* const WB = smem + 16384;

  const int t = threadIdx.x;
  const int bx = blockIdx.x;
  const int b = bx >> 7;
  const int rowbase = (bx & 127) * 64;

  const int wave = t >> 6;
  const int lane = t & 63;
  const int lb = lane & 15;
  const int kg = lane >> 4;
  const unsigned int lxor = (unsigned int)(lb & 7) << 4;

  {
    const int c = t >> 1;
    const int jhalf = t & 1;
    const float4* wp4 = (const float4*)(bigw + (size_t)b * 16384 + (size_t)c * 128 + jhalf * 64);
    const int j0 = jhalf * 64;
#pragma unroll
    for (int q = 0; q < 16; ++q) {
      const float4 v = wp4[q];
      const int j = j0 + q * 4;
      const unsigned int jx0 = (unsigned int)((j + 0) & 7) << 4;
      const unsigned int jx1 = (unsigned int)((j + 1) & 7) << 4;
      const unsigned int jx2 = (unsigned int)((j + 2) & 7) << 4;
      const unsigned int jx3 = (unsigned int)((j + 3) & 7) << 4;
      *(unsigned short*)(WB + (j + 0) * 256 + (((unsigned)(2 * c)) ^ jx0)) = f2bf(v.x);
      *(unsigned short*)(WB + (j + 1) * 256 + (((unsigned)(2 * c)) ^ jx1)) = f2bf(v.y);
      *(unsigned short*)(WB + (j + 2) * 256 + (((unsigned)(2 * c)) ^ jx2)) = f2bf(v.z);
      *(unsigned short*)(WB + (j + 3) * 256 + (((unsigned)(2 * c)) ^ jx3)) = f2bf(v.w);
    }
  }

  float bias[8];
#pragma unroll
  for (int ct = 0; ct < 8; ++ct) bias[ct] = bout[ct * 16 + lb];

  {
    const int r = t >> 2;
    const int cb = (t & 3) * 32;
    const float4* gp4 = (const float4*)(x + (size_t)(b * NN + rowbase + r) * DIM + cb);
    const unsigned int rxor = (unsigned int)(r & 7) << 4;
#pragma unroll
    for (int jj = 0; jj < 4; ++jj) {
      const float4 v0 = gp4[2 * jj];
      const float4 v1 = gp4[2 * jj + 1];
      uint4 u;
      u.x = cvtpk(v0.x, v0.y);
      u.y = cvtpk(v0.z, v0.w);
      u.z = cvtpk(v1.x, v1.y);
      u.w = cvtpk(v1.z, v1.w);
      *(uint4*)(XB + r * 256 + (((unsigned)(2 * cb + 16 * jj)) ^ rxor)) = u;
    }
  }
  __syncthreads();

  f32x4 acc[8];
#pragma unroll
  for (int ct = 0; ct < 8; ++ct) acc[ct] = (f32x4)0.f;
  const int arow = wave * 16 + lb;
#pragma unroll
  for (int ks = 0; ks < 4; ++ks) {
    const unsigned int koff = (unsigned int)(ks * 64 + kg * 16);
    const short8 a = *(const short8*)(XB + arow * 256 + (koff ^ lxor));
#pragma unroll
    for (int ct = 0; ct < 8; ++ct) {
      const short8 bf = *(const short8*)(WB + (ct * 16 + lb) * 256 + (koff ^ lxor));
      acc[ct] = __builtin_amdgcn_mfma_f32_16x16x32_bf16(a, bf, acc[ct], 0, 0, 0);
    }
  }

  float* op = out + (size_t)(b * NN + rowbase + 16 * wave + kg * 4) * DIM;
#pragma unroll
  for (int ct = 0; ct < 8; ++ct) {
#pragma unroll
    for (int reg = 0; reg < 4; ++reg) {
      op[reg * DIM + ct * 16 + lb] = acc[ct][reg] + bias[ct];
    }
  }
}

extern "C" void kernel_launch(void* const* d_in, const int* in_sizes, int n_in,
                              void* d_out, int out_size, void* d_ws, size_t ws_size,
                              hipStream_t stream) {
  (void)in_sizes; (void)n_in; (void)out_size;
  const float* x = (const float*)d_in[0];
  const float* wqkv = (const float*)d_in[1];
  const float* wout = (const float*)d_in[2];
  const float* bout = (const float*)d_in[3];
  float* out = (float*)d_out;

  const size_t NEED = 8388608ull + 262144ull + 131072ull + 524288ull + 2097152ull;
  if (ws_size >= NEED) {
    unsigned char* ximg = (unsigned char*)d_ws;            // 8 MB
    unsigned char* wimg = ximg + 8388608;                  // 256 KB
    unsigned char* bigwimg = wimg + 262144;                // 128 KB
    float* dots = (float*)(bigwimg + 131072);              // 512 KB
    float* part = dots + 131072;                           // 2 MB

    hipLaunchKernelGGL(prep_kernel, dim3(1040), dim3(256), 0, stream, x, wqkv, ximg, wimg, dots);
    hipLaunchKernelGGL(kv_dots_v3, dim3(1024), dim3(512), 0, stream, ximg, wimg, dots);
    hipLaunchKernelGGL((tw_kernel<1>), dim3(128), dim3(256), 0, stream, wqkv, wout, dots, part);
    hipLaunchKernelGGL(bigw_reduce_v2, dim3(32), dim3(256), 0, stream, part, bigwimg);
    hipLaunchKernelGGL(out_v2, dim3(512), dim3(256), 0, stream, ximg, bigwimg, bout, out);
  } else {
    float* dots = (float*)d_ws;
    float* part = dots + 131072;
    float* bigw = part + 524288;
    hipLaunchKernelGGL(zero_dots_fb, dim3(8), dim3(256), 0, stream, dots);
    hipLaunchKernelGGL(kv_dots_fb, dim3(1024), dim3(256), 0, stream, x, wqkv, dots);
    hipLaunchKernelGGL((tw_kernel<0>), dim3(128), dim3(256), 0, stream, wqkv, wout, dots, part);
    hipLaunchKernelGGL(bigw_reduce_fb, dim3(256), dim3(256), 0, stream, part, bigw);
    hipLaunchKernelGGL(out_fb, dim3(512), dim3(256), 0, stream, x, bigw, bout, out);
  }
}

// Round 10
// 65.775 us; speedup vs baseline: 1.0929x; 1.0929x over previous
//
#include <hip/hip_runtime.h>

#define NN 8192
#define DIM 128

typedef short short8 __attribute__((ext_vector_type(8)));
typedef float f32x4 __attribute__((ext_vector_type(4)));

__device__ __forceinline__ unsigned short f2bf(float f) {
  unsigned int u = __float_as_uint(f);
  u = (u + 0x7FFFu + ((u >> 16) & 1u)) >> 16;
  return (unsigned short)u;
}
__device__ __forceinline__ unsigned int cvtpk(float a, float b) {
  unsigned int r;
  asm("v_cvt_pk_bf16_f32 %0, %1, %2" : "=v"(r) : "v"(a), "v"(b));
  return r;
}
__device__ __forceinline__ void gll16(const void* gsrc, void* ldst) {
  __builtin_amdgcn_global_load_lds(
      (const __attribute__((address_space(1))) unsigned int*)gsrc,
      (__attribute__((address_space(3))) unsigned int*)ldst, 16, 0, 0);
}
#define BAR_LGKM()                                          \
  do {                                                      \
    asm volatile("s_waitcnt lgkmcnt(0)" ::: "memory");      \
    __builtin_amdgcn_sched_barrier(0);                      \
    __builtin_amdgcn_s_barrier();                           \
    __builtin_amdgcn_sched_barrier(0);                      \
  } while (0)
#define BAR_VM()                                            \
  do {                                                      \
    asm volatile("s_waitcnt vmcnt(0)" ::: "memory");        \
    __builtin_amdgcn_sched_barrier(0);                      \
    __builtin_amdgcn_s_barrier();                           \
    __builtin_amdgcn_sched_barrier(0);                      \
  } while (0)

// ---------------------------------------------------------------------------
// PREP: blocks 0..1023:  x -> bf16 swizzled tile images (8 MB)
//       blocks 1024..1031: per-head centered W_kv^T bf16 swizzled image
//       blocks 1032..1039: zero `dots`
// x tile image (16 KB per (b,tile64)): byte = r*256 + ((2c) ^ ((r&7)<<4))
// W image (32 KB per head):            byte = c*256 + ((2k) ^ ((c&7)<<4))
// ---------------------------------------------------------------------------
__global__ __launch_bounds__(256) void prep_kernel(const float* __restrict__ x,
                                                   const float* __restrict__ wqkv,
                                                   unsigned char* __restrict__ ximg,
                                                   unsigned char* __restrict__ wimg,
                                                   float* __restrict__ dots) {
  __shared__ __align__(16) unsigned char wb[32768];
  const int t = threadIdx.x;
  const int bx = blockIdx.x;
  if (bx < 1024) {
#pragma unroll
    for (int rep = 0; rep < 2; ++rep) {
      const int idx = bx * 512 + rep * 256 + t;  // 16B chunk index, 0..524287
      const int bt = idx >> 10;                  // b*128 + tile
      const int o = (idx & 1023) << 4;           // byte in 16KB image
      const int r = o >> 8;
      const int q0 = o & 255;
      const int c0 = (q0 ^ ((r & 7) << 4)) >> 1;
      const float* src = x + ((size_t)(bt >> 7) * NN + (size_t)(bt & 127) * 64 + r) * DIM + c0;
      const float4 v0 = *(const float4*)src;
      const float4 v1 = *(const float4*)(src + 4);
      uint4 u;
      u.x = cvtpk(v0.x, v0.y);
      u.y = cvtpk(v0.z, v0.w);
      u.z = cvtpk(v1.x, v1.y);
      u.w = cvtpk(v1.z, v1.w);
      *(uint4*)(ximg + (size_t)idx * 16) = u;
    }
  } else if (bx < 1032) {
    const int h = bx - 1024;
    const int k = t >> 1;
    const int chalf = t & 1;
    const float* wp = wqkv + (size_t)k * 1536 + (chalf ? (1024 + h * 64) : (512 + h * 64));
    const float4* wp4 = (const float4*)wp;
    const int c0 = chalf * 64;
    float4 wv[16];
    float sum = 0.f;
#pragma unroll
    for (int jj = 0; jj < 16; ++jj) {
      wv[jj] = wp4[jj];
      sum += wv[jj].x + wv[jj].y + wv[jj].z + wv[jj].w;
    }
    const float mean = sum * (1.f / 64.f);
#pragma unroll
    for (int jj = 0; jj < 16; ++jj) {
      const int c = c0 + jj * 4;
      const unsigned int cx0 = (unsigned int)((c + 0) & 7) << 4;
      const unsigned int cx1 = (unsigned int)((c + 1) & 7) << 4;
      const unsigned int cx2 = (unsigned int)((c + 2) & 7) << 4;
      const unsigned int cx3 = (unsigned int)((c + 3) & 7) << 4;
      *(unsigned short*)(wb + (c + 0) * 256 + (((unsigned)(2 * k)) ^ cx0)) = f2bf(wv[jj].x - mean);
      *(unsigned short*)(wb + (c + 1) * 256 + (((unsigned)(2 * k)) ^ cx1)) = f2bf(wv[jj].y - mean);
      *(unsigned short*)(wb + (c + 2) * 256 + (((unsigned)(2 * k)) ^ cx2)) = f2bf(wv[jj].z - mean);
      *(unsigned short*)(wb + (c + 3) * 256 + (((unsigned)(2 * k)) ^ cx3)) = f2bf(wv[jj].w - mean);
    }
    __syncthreads();
    const uint4* s4 = (const uint4*)(wb + t * 128);
    uint4* d4 = (uint4*)(wimg + (size_t)h * 32768 + t * 128);
#pragma unroll
    for (int i = 0; i < 8; ++i) d4[i] = s4[i];
  } else {
    const int zb = bx - 1032;
    float4* dz = (float4*)dots + (size_t)zb * 4096 + t;
    const float4 z = make_float4(0.f, 0.f, 0.f, 0.f);
#pragma unroll
    for (int i = 0; i < 16; ++i) dz[i * 256] = z;
  }
}

// ---------------------------------------------------------------------------
// K1 v4: OCCUPANCY-FIRST. 256 thr, LDS 40 KB (W 32 + KT 4 + VT 4) -> 4
// blocks/CU; __launch_bounds__(256,4) caps VGPR<=128 -> 4 waves/SIMD (2x v2).
// 32-row tiles, 8 per block. Wave w = (colhalf=w>>1 [k|v], rowgrp=w&1).
// x A-frags loaded straight to regs from pre-swizzled ximg (double-buffered).
// Each wave scales its own half by its own rsqrt (s_k to K, s_v to V).
// dots: wave w owns d-tile w, K=32 per MFMA, accumulated over 8 tiles.
// ---------------------------------------------------------------------------
__global__ __launch_bounds__(256, 4) void kv_dots_v4(const unsigned char* __restrict__ ximg,
                                                     const unsigned char* __restrict__ wimg,
                                                     float* __restrict__ dots) {
  __shared__ __align__(16) unsigned char smem[40960];
  unsigned char* const WB = smem;          // 32 KB
  unsigned char* const KT = smem + 32768;  // 4 KB [64 d][32 r] swizzled
  unsigned char* const VT = smem + 36864;  // 4 KB [64 e][32 r] swizzled

  const int t = threadIdx.x;
  const int bx = blockIdx.x;
  const int h = bx >> 7;
  const int p = bx & 127;
  const int b = p >> 5;
  const int chunk = p & 31;

  const int wave = t >> 6;
  const int lane = t & 63;
  const int lb = lane & 15;
  const int kg = lane >> 4;
  const int g = wave & 1;    // row group (rows 16g..16g+16 of the 32-row tile)
  const int ch = wave >> 1;  // 0: k cols, 1: v cols
  const unsigned int lxor = (unsigned int)(lb & 7) << 4;
  const unsigned int rxor = (unsigned int)(lb & 3) << 4;

  const unsigned char* wsrc = wimg + (size_t)h * 32768;
  const unsigned char* xsrc = ximg + (size_t)(b * 128 + chunk * 4) * 16384;

  // ---- stage W to LDS ----
#pragma unroll
  for (int i = 0; i < 8; ++i)
    gll16(wsrc + (i * 4 + wave) * 1024 + lane * 16, WB + (i * 4 + wave) * 1024);

  // ---- prologue: tile-0 x A-frags to regs ----
  const int rrow = 16 * g + lb;
  short8 xf[4];
#pragma unroll
  for (int ks = 0; ks < 4; ++ks)
    xf[ks] = *(const short8*)(xsrc + rrow * 256 + (((unsigned)(ks * 64 + kg * 16)) ^ lxor));

  f32x4 dacc[4];
#pragma unroll
  for (int et = 0; et < 4; ++et) dacc[et] = (f32x4)0.f;

  BAR_VM();  // W staged (and prologue x frags complete)

  unsigned char* const MYT = ch ? VT : KT;

  for (int tile = 0; tile < 8; ++tile) {
    // prefetch next tile's x frags
    short8 xn[4];
    if (tile < 7) {
      const unsigned char* tb = xsrc + (size_t)((tile + 1) >> 1) * 16384 + (size_t)((tile + 1) & 1) * 8192;
#pragma unroll
      for (int ks = 0; ks < 4; ++ks)
        xn[ks] = *(const short8*)(tb + rrow * 256 + (((unsigned)(ks * 64 + kg * 16)) ^ lxor));
    }

    // ---- my half of kv = x @ W' (16 MFMAs) ----
    f32x4 acc[4];
#pragma unroll
    for (int ct = 0; ct < 4; ++ct) acc[ct] = (f32x4)0.f;
#pragma unroll
    for (int ks = 0; ks < 4; ++ks) {
      const unsigned int koff = ((unsigned)(ks * 64 + kg * 16)) ^ lxor;
#pragma unroll
      for (int ct = 0; ct < 4; ++ct) {
        const short8 bf = *(const short8*)(WB + (ch * 64 + ct * 16 + lb) * 256 + koff);
        acc[ct] = __builtin_amdgcn_mfma_f32_16x16x32_bf16(xf[ks], bf, acc[ct], 0, 0, 0);
      }
    }

    // ---- variance of my half (inputs centered via W'), scale my side ----
    float sc[4];
#pragma unroll
    for (int e = 0; e < 4; ++e) {
      float s = acc[0][e] * acc[0][e] + acc[1][e] * acc[1][e] +
                acc[2][e] * acc[2][e] + acc[3][e] * acc[3][e];
      s += __shfl_xor(s, 1);
      s += __shfl_xor(s, 2);
      s += __shfl_xor(s, 4);
      s += __shfl_xor(s, 8);
      sc[e] = rsqrtf(s * (1.f / 64.f) + 1e-5f);
    }

    // ---- write my transposed half (scaled), wave-exclusive byte ranges ----
    {
      const unsigned int rb = ((unsigned)(g * 32 + kg * 8)) ^ rxor;
#pragma unroll
      for (int ct = 0; ct < 4; ++ct) {
        uint2 w2;
        w2.x = cvtpk(acc[ct][0] * sc[0], acc[ct][1] * sc[1]);
        w2.y = cvtpk(acc[ct][2] * sc[2], acc[ct][3] * sc[3]);
        *(uint2*)(MYT + (ct * 16 + lb) * 64 + rb) = w2;
      }
    }
    BAR_LGKM();

    // ---- dots += kT @ v : wave owns d-tile `wave`, 4 MFMAs (K=32) ----
    {
      const unsigned int soff = ((unsigned)(kg * 16)) ^ rxor;
      const short8 a = *(const short8*)(KT + (wave * 16 + lb) * 64 + soff);
#pragma unroll
      for (int et = 0; et < 4; ++et) {
        const short8 bf = *(const short8*)(VT + (et * 16 + lb) * 64 + soff);
        dacc[et] = __builtin_amdgcn_mfma_f32_16x16x32_bf16(a, bf, dacc[et], 0, 0, 0);
      }
    }
    BAR_LGKM();  // all dots reads done before next tile's KT/VT overwrite

#pragma unroll
    for (int ks = 0; ks < 4; ++ks) xf[ks] = xn[ks];
  }

  float* dp = dots + (size_t)(b * 8 + h) * 4096;
#pragma unroll
  for (int et = 0; et < 4; ++et) {
#pragma unroll
    for (int reg = 0; reg < 4; ++reg) {
      const int d = wave * 16 + kg * 4 + reg;
      const int e = et * 16 + lb;
      atomicAdd(&dp[d * 64 + e], dacc[et][reg]);
    }
  }
}

// ---------------------------------------------------------------------------
// K2 (fused t + bigw), c-split. TR=1: store part transposed [j][c].
// ---------------------------------------------------------------------------
template <int TR>
__global__ __launch_bounds__(256) void tw_kernel(const float* __restrict__ wqkv,
                                                 const float* __restrict__ wout,
                                                 const float* __restrict__ dots,
                                                 float* __restrict__ part) {
  __shared__ __align__(16) float ds[64 * 66];
  __shared__ __align__(16) float wqT[64 * 36];
  __shared__ __align__(16) float Ts[32 * 66];
  __shared__ __align__(16) float wos[64 * 132];

  const int blk = blockIdx.x;
  const int bh = blk >> 2;
  const int cq = blk & 3;
  const int h = bh & 7;
  const int t = threadIdx.x;

  for (int i = t; i < 4096; i += 256)
    ds[(i >> 6) * 66 + (i & 63)] = dots[(size_t)bh * 4096 + i];

  for (int i = t; i < 2048; i += 256) {
    const int d = i >> 5;
    const int c = i & 31;
    wqT[d * 36 + c] = wqkv[(size_t)(cq * 32 + c) * 1536 + h * 64 + d];
  }

  for (int i = t; i < 2048; i += 256) {
    const int e = i >> 5;
    const int jj = (i & 31) * 4;
    *(float4*)&wos[e * 132 + jj] = *(const float4*)(wout + (size_t)(h * 64 + e) * 128 + jj);
  }
  __syncthreads();

  {
    const int c = t >> 3;
    const int e0 = (t & 7) * 8;
    float acc[8];
#pragma unroll
    for (int q = 0; q < 8; ++q) acc[q] = 0.f;
    for (int d = 0; d < 64; ++d) {
      const float wq = wqT[d * 36 + c];
      const float4 d0 = *(const float4*)&ds[d * 66 + e0];
      const float4 d1 = *(const float4*)&ds[d * 66 + e0 + 4];
      acc[0] += wq * d0.x; acc[1] += wq * d0.y; acc[2] += wq * d0.z; acc[3] += wq * d0.w;
      acc[4] += wq * d1.x; acc[5] += wq * d1.y; acc[6] += wq * d1.z; acc[7] += wq * d1.w;
    }
    *(float4*)&Ts[c * 66 + e0] = make_float4(acc[0], acc[1], acc[2], acc[3]);
    *(float4*)&Ts[c * 66 + e0 + 4] = make_float4(acc[4], acc[5], acc[6], acc[7]);
  }
  __syncthreads();

  {
    const int c = t >> 3;
    const int j0 = (t & 7) * 16;
    float acc[16];
#pragma unroll
    for (int q = 0; q < 16; ++q) acc[q] = 0.f;
    for (int e = 0; e < 64; ++e) {
      const float tv = Ts[c * 66 + e];
#pragma unroll
      for (int q = 0; q < 16; q += 4) {
        const float4 wv = *(const float4*)&wos[e * 132 + j0 + q];
        acc[q + 0] += tv * wv.x;
        acc[q + 1] += tv * wv.y;
        acc[q + 2] += tv * wv.z;
        acc[q + 3] += tv * wv.w;
      }
    }
    if (TR) {
      float* pp = part + (size_t)bh * 16384;
      const int cc = cq * 32 + c;
#pragma unroll
      for (int q = 0; q < 16; ++q) pp[(j0 + q) * 128 + cc] = acc[q];
    } else {
      float* pp = part + (size_t)bh * 16384 + (size_t)(cq * 32 + c) * 128 + j0;
#pragma unroll
      for (int q = 0; q < 16; q += 4)
        *(float4*)&pp[q] = make_float4(acc[q], acc[q + 1], acc[q + 2], acc[q + 3]);
    }
  }
}

// ---------------------------------------------------------------------------
// K2r v2: bigwimg (bf16, swizzled) = (1/n) * sum_h part_T[b,h][j][c]
// ---------------------------------------------------------------------------
__global__ __launch_bounds__(256) void bigw_reduce_v2(const float* __restrict__ part,
                                                      unsigned char* __restrict__ bigwimg) {
  const int idx = blockIdx.x * 256 + threadIdx.x;  // 16B chunk, 0..8191
  const int b = idx >> 11;
  const int o = (idx & 2047) << 4;
  const int j = o >> 8;
  const int q0 = o & 255;
  const int c0 = (q0 ^ ((j & 7) << 4)) >> 1;
  float s[8];
#pragma unroll
  for (int i = 0; i < 8; ++i) s[i] = 0.f;
  const float* pb = part + (size_t)b * 8 * 16384 + j * 128 + c0;
#pragma unroll
  for (int hh = 0; hh < 8; ++hh) {
    const float4 p0 = *(const float4*)(pb + hh * 16384);
    const float4 p1 = *(const float4*)(pb + hh * 16384 + 4);
    s[0] += p0.x; s[1] += p0.y; s[2] += p0.z; s[3] += p0.w;
    s[4] += p1.x; s[5] += p1.y; s[6] += p1.z; s[7] += p1.w;
  }
  const float inv_n = 1.f / (float)NN;
  uint4 u;
  u.x = cvtpk(s[0] * inv_n, s[1] * inv_n);
  u.y = cvtpk(s[2] * inv_n, s[3] * inv_n);
  u.z = cvtpk(s[4] * inv_n, s[5] * inv_n);
  u.w = cvtpk(s[6] * inv_n, s[7] * inv_n);
  *(uint4*)(bigwimg + (size_t)idx * 16) = u;
}

// ---------------------------------------------------------------------------
// K3 v2: out = x @ BigW + bias, pure gll staging. 48 KB LDS, grid 512.
// ---------------------------------------------------------------------------
__global__ __launch_bounds__(256) void out_v2(const unsigned char* __restrict__ ximg,
                                              const unsigned char* __restrict__ bigwimg,
                                              const float* __restrict__ bout,
                                              float* __restrict__ out) {
  __shared__ __align__(16) unsigned char smem[49152];
  unsigned char* const XB = smem;
  unsigned char* const WJ = smem + 16384;

  const int t = threadIdx.x;
  const int bx = blockIdx.x;
  const int b = bx >> 7;
  const int tile = bx & 127;

  const int wave = t >> 6;
  const int lane = t & 63;
  const int lb = lane & 15;
  const int kg = lane >> 4;
  const unsigned int lxor = (unsigned int)(lb & 7) << 4;

  const unsigned char* wsrc = bigwimg + (size_t)b * 32768;
  const unsigned char* xsrc = ximg + (size_t)(b * 128 + tile) * 16384;

#pragma unroll
  for (int i = 0; i < 8; ++i)
    gll16(wsrc + (wave * 8 + i) * 1024 + lane * 16, WJ + (wave * 8 + i) * 1024);
#pragma unroll
  for (int i = 0; i < 4; ++i)
    gll16(xsrc + (wave * 4 + i) * 1024 + lane * 16, XB + (wave * 4 + i) * 1024);

  float bias[8];
#pragma unroll
  for (int ct = 0; ct < 8; ++ct) bias[ct] = bout[ct * 16 + lb];

  BAR_VM();

  f32x4 acc[8];
#pragma unroll
  for (int ct = 0; ct < 8; ++ct) acc[ct] = (f32x4)0.f;
  const int arow = wave * 16 + lb;
#pragma unroll
  for (int ks = 0; ks < 4; ++ks) {
    const unsigned int koff = (unsigned int)(ks * 64 + kg * 16);
    const short8 a = *(const short8*)(XB + arow * 256 + (koff ^ lxor));
#pragma unroll
    for (int ct = 0; ct < 8; ++ct) {
      const short8 bf = *(const short8*)(WJ + (ct * 16 + lb) * 256 + (koff ^ lxor));
      acc[ct] = __builtin_amdgcn_mfma_f32_16x16x32_bf16(a, bf, acc[ct], 0, 0, 0);
    }
  }

  float* op = out + (size_t)(b * NN + tile * 64 + 16 * wave + kg * 4) * DIM;
#pragma unroll
  for (int ct = 0; ct < 8; ++ct) {
#pragma unroll
    for (int reg = 0; reg < 4; ++reg) {
      op[reg * DIM + ct * 16 + lb] = acc[ct][reg] + bias[ct];
    }
  }
}

// ===========================================================================
// Fallback path (known-good) used if ws_size is too small for the images.
// ===========================================================================
__global__ __launch_bounds__(256) void zero_dots_fb(float* __restrict__ dots) {
  float4* dz = (float4*)dots + (size_t)blockIdx.x * 4096 + threadIdx.x;
  const float4 z = make_float4(0.f, 0.f, 0.f, 0.f);
#pragma unroll
  for (int i = 0; i < 16; ++i) dz[i * 256] = z;
}

__global__ __launch_bounds__(256) void kv_dots_fb(const float* __restrict__ x,
                                                  const float* __restrict__ wqkv,
                                                  float* __restrict__ dots) {
  __shared__ __align__(16) unsigned char smem[49152];
  unsigned char* const XB = smem;
  unsigned char* const KT = smem;
  unsigned char* const VT = smem + 8192;
  unsigned char* const WB = smem + 16384;

  const int t = threadIdx.x;
  const int bx = blockIdx.x;
  const int h = bx >> 7;
  const int p = bx & 127;
  const int b = p >> 5;
  const int chunk = p & 31;
  const int row0 = chunk * 256;

  const int wave = t >> 6;
  const int lane = t & 63;
  const int lb = lane & 15;
  const int kg = lane >> 4;
  const unsigned int lxor = (unsigned int)(lb & 7) << 4;

  {
    const int k = t >> 1;
    const int chalf = t & 1;
    const float* wp = wqkv + (size_t)k * 1536 + (chalf ? (1024 + h * 64) : (512 + h * 64));
    const float4* wp4 = (const float4*)wp;
    const int c0 = chalf * 64;
    float4 wv[16];
    float sum = 0.f;
#pragma unroll
    for (int jj = 0; jj < 16; ++jj) {
      wv[jj] = wp4[jj];
      sum += wv[jj].x + wv[jj].y + wv[jj].z + wv[jj].w;
    }
    const float mean = sum * (1.f / 64.f);
#pragma unroll
    for (int jj = 0; jj < 16; ++jj) {
      const int c = c0 + jj * 4;
      const unsigned int cx0 = (unsigned int)((c + 0) & 7) << 4;
      const unsigned int cx1 = (unsigned int)((c + 1) & 7) << 4;
      const unsigned int cx2 = (unsigned int)((c + 2) & 7) << 4;
      const unsigned int cx3 = (unsigned int)((c + 3) & 7) << 4;
      *(unsigned short*)(WB + (c + 0) * 256 + (((unsigned)(2 * k)) ^ cx0)) = f2bf(wv[jj].x - mean);
      *(unsigned short*)(WB + (c + 1) * 256 + (((unsigned)(2 * k)) ^ cx1)) = f2bf(wv[jj].y - mean);
      *(unsigned short*)(WB + (c + 2) * 256 + (((unsigned)(2 * k)) ^ cx2)) = f2bf(wv[jj].z - mean);
      *(unsigned short*)(WB + (c + 3) * 256 + (((unsigned)(2 * k)) ^ cx3)) = f2bf(wv[jj].w - mean);
    }
  }

  f32x4 dacc[4];
#pragma unroll
  for (int nt = 0; nt < 4; ++nt) dacc[nt] = (f32x4)0.f;

  __syncthreads();

  for (int tile = 0; tile < 4; ++tile) {
    const int rowbase = row0 + tile * 64;
    __syncthreads();
    {
      const int r = t >> 2;
      const int cb = (t & 3) * 32;
      const float4* gp4 = (const float4*)(x + (size_t)(b * NN + rowbase + r) * DIM + cb);
      const unsigned int rxor = (unsigned int)(r & 7) << 4;
#pragma unroll
      for (int jj = 0; jj < 4; ++jj) {
        const float4 v0 = gp4[2 * jj];
        const float4 v1 = gp4[2 * jj + 1];
        uint4 u;
        u.x = cvtpk(v0.x, v0.y);
        u.y = cvtpk(v0.z, v0.w);
        u.z = cvtpk(v1.x, v1.y);
        u.w = cvtpk(v1.z, v1.w);
        *(uint4*)(XB + r * 256 + (((unsigned)(2 * cb + 16 * jj)) ^ rxor)) = u;
      }
    }
    __syncthreads();

    f32x4 acc[8];
#pragma unroll
    for (int ct = 0; ct < 8; ++ct) acc[ct] = (f32x4)0.f;
    const int arow = wave * 16 + lb;
#pragma unroll
    for (int ks = 0; ks < 4; ++ks) {
      const unsigned int koff = (unsigned int)(ks * 64 + kg * 16);
      const short8 a = *(const short8*)(XB + arow * 256 + (koff ^ lxor));
#pragma unroll
      for (int ct = 0; ct < 8; ++ct) {
        const short8 bf = *(const short8*)(WB + (ct * 16 + lb) * 256 + (koff ^ lxor));
        acc[ct] = __builtin_amdgcn_mfma_f32_16x16x32_bf16(a, bf, acc[ct], 0, 0, 0);
      }
    }

    float kscale[4];
#pragma unroll
    for (int e = 0; e < 4; ++e) {
      float sk = acc[0][e] * acc[0][e] + acc[1][e] * acc[1][e] +
                 acc[2][e] * acc[2][e] + acc[3][e] * acc[3][e];
      float sv = acc[4][e] * acc[4][e] + acc[5][e] * acc[5][e] +
                 acc[6][e] * acc[6][e] + acc[7][e] * acc[7][e];
      sk += __shfl_xor(sk, 1); sv += __shfl_xor(sv, 1);
      sk += __shfl_xor(sk, 2); sv += __shfl_xor(sv, 2);
      sk += __shfl_xor(sk, 4); sv += __shfl_xor(sv, 4);
      sk += __shfl_xor(sk, 8); sv += __shfl_xor(sv, 8);
      kscale[e] = rsqrtf(sk * (1.f / 64.f) + 1e-5f) * rsqrtf(sv * (1.f / 64.f) + 1e-5f);
    }

    __syncthreads();
    {
      const unsigned int rb2 = (unsigned int)(32 * wave + kg * 8);
#pragma unroll
      for (int ct = 0; ct < 4; ++ct) {
        uint2 w;
        w.x = cvtpk(acc[ct][0] * kscale[0], acc[ct][1] * kscale[1]);
        w.y = cvtpk(acc[ct][2] * kscale[2], acc[ct][3] * kscale[3]);
        *(uint2*)(KT + (ct * 16 + lb) * 128 + (rb2 ^ lxor)) = w;
      }
#pragma unroll
      for (int ct = 4; ct < 8; ++ct) {
        uint2 w;
        w.x = cvtpk(acc[ct][0], acc[ct][1]);
        w.y = cvtpk(acc[ct][2], acc[ct][3]);
        *(uint2*)(VT + ((ct - 4) * 16 + lb) * 128 + (rb2 ^ lxor)) = w;
      }
    }
    __syncthreads();

#pragma unroll
    for (int ks2 = 0; ks2 < 2; ++ks2) {
      const unsigned int koff = (unsigned int)(ks2 * 64 + kg * 16);
      const short8 a = *(const short8*)(KT + (wave * 16 + lb) * 128 + (koff ^ lxor));
#pragma unroll
      for (int nt = 0; nt < 4; ++nt) {
        const short8 bf = *(const short8*)(VT + (nt * 16 + lb) * 128 + (koff ^ lxor));
        dacc[nt] = __builtin_amdgcn_mfma_f32_16x16x32_bf16(a, bf, dacc[nt], 0, 0, 0);
      }
    }
  }

  float* dp = dots + (size_t)(b * 8 + h) * 4096;
#pragma unroll
  for (int nt = 0; nt < 4; ++nt) {
#pragma unroll
    for (int reg = 0; reg < 4; ++reg) {
      const int d = 16 * wave + kg * 4 + reg;
      const int e = nt * 16 + lb;
      atomicAdd(&dp[d * 64 + e], dacc[nt][reg]);
    }
  }
}

__global__ __launch_bounds__(256) void bigw_reduce_fb(const float* __restrict__ part,
                                                      float* __restrict__ bigw) {
  const int i = blockIdx.x * 256 + threadIdx.x;
  const int b = i >> 14;
  const int cj = i & 16383;
  const float* pp = part + (size_t)b * 8 * 16384 + cj;
  float s = 0.f;
#pragma unroll
  for (int h = 0; h < 8; ++h) s += pp[h * 16384];
  bigw[i] = s * (1.f / (float)NN);
}

__global__ __launch_bounds__(256) void out_fb(const float* __restrict__ x,
                                              const float* __restrict__ bigw,
                                              const float* __restrict__ bout,
                                              float* __restrict__ out) {
  __shared__ __align__(16) unsigned char smem[49152];
  unsigned char* const XB = smem;
  unsigned char* const WB = smem + 16384;

  const int t = threadIdx.x;
  const int bx = blockIdx.x;
  const int b = bx >> 7;
  const int rowbase = (bx & 127) * 64;

  const int wave = t >> 6;
  const int lane = t & 63;
  const int lb = lane & 15;
  const int kg = lane >> 4;
  const unsigned int lxor = (unsigned int)(lb & 7) << 4;

  {
    const int c = t >> 1;
    const int jhalf = t & 1;
    const float4* wp4 = (const float4*)(bigw + (size_t)b * 16384 + (size_t)c * 128 + jhalf * 64);
    const int j0 = jhalf * 64;
#pragma unroll
    for (int q = 0; q < 16; ++q) {
      const float4 v = wp4[q];
      const int j = j0 + q * 4;
      const unsigned int jx0 = (unsigned int)((j + 0) & 7) << 4;
      const unsigned int jx1 = (unsigned int)((j + 1) & 7) << 4;
      const unsigned int jx2 = (unsigned int)((j + 2) & 7) << 4;
      const unsigned int jx3 = (unsigned int)((j + 3) & 7) << 4;
      *(unsigned short*)(WB + (j + 0) * 256 + (((unsigned)(2 * c)) ^ jx0)) = f2bf(v.x);
      *(unsigned short*)(WB + (j + 1) * 256 + (((unsigned)(2 * c)) ^ jx1)) = f2bf(v.y);
      *(unsigned short*)(WB + (j + 2) * 256 + (((unsigned)(2 * c)) ^ jx2)) = f2bf(v.z);
      *(unsigned short*)(WB + (j + 3) * 256 + (((unsigned)(2 * c)) ^ jx3)) = f2bf(v.w);
    }
  }

  float bias[8];
#pragma unroll
  for (int ct = 0; ct < 8; ++ct) bias[ct] = bout[ct * 16 + lb];

  {
    const int r = t >> 2;
    const int cb = (t & 3) * 32;
    const float4* gp4 = (const float4*)(x + (size_t)(b * NN + rowbase + r) * DIM + cb);
    const unsigned int rxor = (unsigned int)(r & 7) << 4;
#pragma unroll
    for (int jj = 0; jj < 4; ++jj) {
      const float4 v0 = gp4[2 * jj];
      const float4 v1 = gp4[2 * jj + 1];
      uint4 u;
      u.x = cvtpk(v0.x, v0.y);
      u.y = cvtpk(v0.z, v0.w);
      u.z = cvtpk(v1.x, v1.y);
      u.w = cvtpk(v1.z, v1.w);
      *(uint4*)(XB + r * 256 + (((unsigned)(2 * cb + 16 * jj)) ^ rxor)) = u;
    }
  }
  __syncthreads();

  f32x4 acc[8];
#pragma unroll
  for (int ct = 0; ct < 8; ++ct) acc[ct] = (f32x4)0.f;
  const int arow = wave * 16 + lb;
#pragma unroll
  for (int ks = 0; ks < 4; ++ks) {
    const unsigned int koff = (unsigned int)(ks * 64 + kg * 16);
    const short8 a = *(const short8*)(XB + arow * 256 + (koff ^ lxor));
#pragma unroll
    for (int ct = 0; ct < 8; ++ct) {
      const short8 bf = *(const short8*)(WB + (ct * 16 + lb) * 256 + (koff ^ lxor));
      acc[ct] = __builtin_amdgcn_mfma_f32_16x16x32_bf16(a, bf, acc[ct], 0, 0, 0);
    }
  }

  float* op = out + (size_t)(b * NN + rowbase + 16 * wave + kg * 4) * DIM;
#pragma unroll
  for (int ct = 0; ct < 8; ++ct) {
#pragma unroll
    for (int reg = 0; reg < 4; ++reg) {
      op[reg * DIM + ct * 16 + lb] = acc[ct][reg] + bias[ct];
    }
  }
}

extern "C" void kernel_launch(void* const* d_in, const int* in_sizes, int n_in,
                              void* d_out, int out_size, void* d_ws, size_t ws_size,
                              hipStream_t stream) {
  (void)in_sizes; (void)n_in; (void)out_size;
  const float* x = (const float*)d_in[0];
  const float* wqkv = (const float*)d_in[1];
  const float* wout = (const float*)d_in[2];
  const float* bout = (const float*)d_in[3];
  float* out = (float*)d_out;

  const size_t NEED = 8388608ull + 262144ull + 131072ull + 524288ull + 2097152ull;
  if (ws_size >= NEED) {
    unsigned char* ximg = (unsigned char*)d_ws;            // 8 MB
    unsigned char* wimg = ximg + 8388608;                  // 256 KB
    unsigned char* bigwimg = wimg + 262144;                // 128 KB
    float* dots = (float*)(bigwimg + 131072);              // 512 KB
    float* part = dots + 131072;                           // 2 MB

    hipLaunchKernelGGL(prep_kernel, dim3(1040), dim3(256), 0, stream, x, wqkv, ximg, wimg, dots);
    hipLaunchKernelGGL(kv_dots_v4, dim3(1024), dim3(256), 0, stream, ximg, wimg, dots);
    hipLaunchKernelGGL((tw_kernel<1>), dim3(128), dim3(256), 0, stream, wqkv, wout, dots, part);
    hipLaunchKernelGGL(bigw_reduce_v2, dim3(32), dim3(256), 0, stream, part, bigwimg);
    hipLaunchKernelGGL(out_v2, dim3(512), dim3(256), 0, stream, ximg, bigwimg, bout, out);
  } else {
    float* dots = (float*)d_ws;
    float* part = dots + 131072;
    float* bigw = part + 524288;
    hipLaunchKernelGGL(zero_dots_fb, dim3(8), dim3(256), 0, stream, dots);
    hipLaunchKernelGGL(kv_dots_fb, dim3(1024), dim3(256), 0, stream, x, wqkv, dots);
    hipLaunchKernelGGL((tw_kernel<0>), dim3(128), dim3(256), 0, stream, wqkv, wout, dots, part);
    hipLaunchKernelGGL(bigw_reduce_fb, dim3(256), dim3(256), 0, stream, part, bigw);
    hipLaunchKernelGGL(out_fb, dim3(512), dim3(256), 0, stream, x, bigw, bout, out);
  }
}